// Round 1
// baseline (260.294 us; speedup 1.0000x reference)
//
#include <hip/hip_runtime.h>

#define BB 16
#define TT 2048
#define NFREQ 513
#define MHALF 512
#define HOP 256
#define WIN 1024
#define LPAD 525056   // (TT-1)*HOP + WIN
#define PAD 384
#define OUTL 524288   // LPAD - 2*PAD
#define FT 8
#define OLA_LEN (FT*HOP + (WIN-HOP))   // 2816

__device__ __forceinline__ int brev9(int k) {
  return (int)(__brev((unsigned)k) >> 23);
}

// One block = one batch b, FT consecutive frames. 256 threads.
__global__ __launch_bounds__(256) void istft_frames(
    const float* __restrict__ sr, const float* __restrict__ si,
    float* __restrict__ y)
{
  __shared__ float zr[MHALF][FT + 1];   // +1 pad: odd stride 9 breaks bank conflicts
  __shared__ float zi[MHALF][FT + 1];
  __shared__ float ola[OLA_LEN];
  __shared__ float twc[256], tws[256];

  const int tid  = threadIdx.x;
  const int b    = blockIdx.x / (TT / FT);
  const int tile = blockIdx.x % (TT / FT);
  const int t0   = tile * FT;

  // twiddle table: e^{+i*2pi*j/512}, j in [0,256)
  {
    float s, c;
    __sincosf((float)tid * 0.01227184630308513f, &s, &c);
    twc[tid] = c; tws[tid] = s;
  }
  for (int i = tid; i < OLA_LEN; i += 256) ola[i] = 0.f;

  // ---- Phase 1: load spec, build packed spectrum Z (bit-reversed store) ----
  const int f  = tid & (FT - 1);      // frame within tile
  const int kg = tid >> 3;            // [0,32)
  const float* srb = sr + (size_t)b * NFREQ * TT + t0 + f;
  const float* sib = si + (size_t)b * NFREQ * TT + t0 + f;

  for (int c = 0; c < 8; ++c) {
    int k = c * 32 + kg;              // [0,256)
    float ar  = srb[(size_t)k * TT];
    float ai  = sib[(size_t)k * TT];
    float br_ = srb[(size_t)(MHALF - k) * TT];
    float bi_ = sib[(size_t)(MHALF - k) * TT];
    if (k == 0) {
      // bins 0 and 512: imag parts ignored (pocketfft c2r semantics)
      zr[0][f] = 0.5f * (ar + br_);
      zi[0][f] = 0.5f * (ar - br_);
      // k=256: Z[256] = conj(X[256]); brev9(256)=1
      float cr = srb[(size_t)256 * TT];
      float ci = sib[(size_t)256 * TT];
      zr[1][f] = cr;
      zi[1][f] = -ci;
    } else {
      float st, ct;
      __sincosf((float)k * 0.006135923151542565f, &st, &ct); // pi*k/512
      float Er = 0.5f * (ar + br_), Ei = 0.5f * (ai - bi_);
      float Dr = 0.5f * (ar - br_), Di = 0.5f * (ai + bi_);
      float Or = Dr * ct - Di * st,  Oi = Dr * st + Di * ct;
      int p  = brev9(k);
      zr[p][f]  = Er - Oi;
      zi[p][f]  = Ei + Or;
      // Z[512-k] = conj(E) + i*conj(O)
      int p2 = brev9(MHALF - k);
      zr[p2][f] = Er + Oi;
      zi[p2][f] = Or - Ei;
    }
  }

  // ---- Phase 2: 512-pt complex inverse DFT (DIT radix-2, e^{+i}) ----
  const int pp = tid >> 3;            // [0,32) butterfly lanes per frame
  for (int s = 0; s < 9; ++s) {
    __syncthreads();
    const int h = 1 << s;
    #pragma unroll
    for (int i = 0; i < 8; ++i) {
      int bf  = pp + 32 * i;          // [0,256)
      int ilo = bf & (h - 1);
      int ihi = bf >> s;
      int i0  = ihi * (h << 1) + ilo;
      int i1  = i0 + h;
      int tj  = ilo << (8 - s);
      float wr = twc[tj], wi = tws[tj];
      float ur = zr[i0][f], ui = zi[i0][f];
      float vr = zr[i1][f], vi = zi[i1][f];
      float tr = vr * wr - vi * wi;
      float ti = vr * wi + vi * wr;
      zr[i0][f] = ur + tr; zi[i0][f] = ui + ti;
      zr[i1][f] = ur - tr; zi[i1][f] = ui - ti;
    }
  }

  // ---- Phase 3: unpack, window, overlap-add in LDS ----
  // frames g and g+4 (1024 apart * ... regions disjoint) per group -> no races
  for (int g = 0; g < 4; ++g) {
    __syncthreads();
    int fr = g + 4 * (tid >> 7);
    int mb = tid & 127;
    #pragma unroll
    for (int i = 0; i < 4; ++i) {
      int m = mb + 128 * i;
      float re = zr[m][fr] * (1.0f / 512.0f);
      float im = zi[m][fr] * (1.0f / 512.0f);
      int j0 = 2 * m;
      float w0 = 0.5f - 0.5f * __cosf((float)j0       * 0.006135923151542565f);
      float w1 = 0.5f - 0.5f * __cosf((float)(j0 + 1) * 0.006135923151542565f);
      ola[fr * HOP + j0]     += re * w0;
      ola[fr * HOP + j0 + 1] += im * w1;
    }
  }
  __syncthreads();

  // ---- Phase 4: LDS -> global. Interior exclusive: plain store; halos: atomic ----
  size_t ybase = (size_t)b * LPAD + (size_t)t0 * HOP;
  for (int i = 0; i < OLA_LEN / 256; ++i) {
    int idx = tid + 256 * i;
    float v = ola[idx];
    if (idx < (WIN - HOP) || idx >= FT * HOP) atomicAdd(&y[ybase + idx], v);
    else                                      y[ybase + idx] = v;
  }
}

// Divide by OLA'd window^2 envelope, slice [PAD, LPAD-PAD)
__global__ __launch_bounds__(256) void istft_finalize(
    const float* __restrict__ y, const float* __restrict__ w,
    float* __restrict__ out)
{
  int gid = blockIdx.x * 256 + threadIdx.x;       // [0, BB*OUTL/4)
  int b   = gid >> 17;                            // OUTL/4 = 2^17
  int oo  = (gid & 131071) << 2;
  const float* yp = y + (size_t)b * LPAD + PAD + oo;
  float4 v = *(const float4*)yp;
  float r[4] = {v.x, v.y, v.z, v.w};
  float o[4];
  int l0 = PAD + oo;
  if (l0 >= (WIN - HOP) && l0 + 3 <= (TT - 1) * HOP + HOP - 1) {
    // interior: env == 1.5 exactly (Hann, 4x overlap)
    #pragma unroll
    for (int i = 0; i < 4; ++i) o[i] = r[i] * (2.0f / 3.0f);
  } else {
    #pragma unroll
    for (int i = 0; i < 4; ++i) {
      int l  = l0 + i;
      int j0 = l & 255;
      int tb = l >> 8;
      float env = 0.f;
      #pragma unroll
      for (int m2 = 0; m2 < 4; ++m2) {
        int t = tb - m2;
        if (t >= 0 && t < TT) { float ww = w[j0 + 256 * m2]; env += ww * ww; }
      }
      o[i] = r[i] / env;
    }
  }
  float4 vo = make_float4(o[0], o[1], o[2], o[3]);
  *(float4*)(out + ((size_t)gid << 2)) = vo;
}

extern "C" void kernel_launch(void* const* d_in, const int* in_sizes, int n_in,
                              void* d_out, int out_size, void* d_ws, size_t ws_size,
                              hipStream_t stream) {
  const float* sr = (const float*)d_in[0];
  const float* si = (const float*)d_in[1];
  const float* w  = (const float*)d_in[2];
  float* y   = (float*)d_ws;
  float* out = (float*)d_out;

  hipMemsetAsync(d_ws, 0, (size_t)BB * LPAD * sizeof(float), stream);
  istft_frames<<<BB * (TT / FT), 256, 0, stream>>>(sr, si, y);
  istft_finalize<<<(BB * (OUTL / 4)) / 256, 256, 0, stream>>>(y, w, out);
}

// Round 2
// 260.144 us; speedup vs baseline: 1.0006x; 1.0006x over previous
//
#include <hip/hip_runtime.h>

#define BB 16
#define TT 2048
#define NROW 513
#define HOP 256
#define OUTLB 524288          // out length per batch
#define FTO 28                // output frames per block
#define SPAN (FTO*HOP)        // 7168
#define TILES 74              // ceil(2048/28)
#define NCH 4                 // 4 chunks x 8 frames = 32 = FTO+4 exactly
#define RZ 513                // z row stride in complex (odd => additive f bank spread)

__device__ __forceinline__ int brev9(int k){ return (int)(__brev((unsigned)k)>>23); }
// swizzled LDS index for frame f, logical complex position m in [0,512)
// bank(b64) = (f*513 + pc) % 32 ; XOR mixes high bits + frame id -> <=2-way a.e.
__device__ __forceinline__ int zidx(int f,int m){ return f*RZ + (m ^ ((m>>4)&28) ^ (f<<2)); }

__global__ __launch_bounds__(256,2) void istft_fused(
    const float* __restrict__ sr, const float* __restrict__ si,
    float* __restrict__ out)
{
  __shared__ float2 zc[8*RZ];                       // 32832 B
  __shared__ __align__(16) float2 ola[SPAN/2];      // 28672 B
  __shared__ float2 ttab[256];                      // 2048 B  => 63552 B total

  const int tid  = threadIdx.x;
  const int b    = blockIdx.x / TILES;
  const int tile = blockIdx.x % TILES;
  const int L0   = tile*SPAN + 384;                 // y-index of span start
  const int Tbase= tile*FTO - 2;

  // twiddles W^j = e^{+2pi i j/512}, j in [0,256)
  { float s,c; __sincosf((float)tid*0.012271846303085130f,&s,&c); ttab[tid]=make_float2(c,s); }
  for (int i=tid;i<SPAN/2;i+=256) ola[i]=make_float2(0.f,0.f);

  const int f  = tid & 7;                           // frame slot within chunk
  const int pp = tid >> 3;                          // [0,32)
  const float* srb = sr + (size_t)b*NROW*TT;
  const float* sib = si + (size_t)b*NROW*TT;

  for (int c = 0; c < NCH; ++c) {
    const int t  = Tbase + 8*c + f;
    const int tc = min(max(t,0),TT-1);
    const float msk = (t>=0 && t<TT) ? 1.f : 0.f;
    __syncthreads();                                // zc reuse (WAR vs prev phase3)

    // ---- phase 1: build packed spectrum Z, store digit(bit)-reversed ----
    for (int cc=0; cc<8; ++cc) {
      int k = cc*32 + pp;                           // [0,256)
      float ar = srb[(size_t)k*TT + tc]*msk;
      float ai = sib[(size_t)k*TT + tc]*msk;
      float br = srb[(size_t)(512-k)*TT + tc]*msk;
      float bi = sib[(size_t)(512-k)*TT + tc]*msk;
      if (k==0) {
        zc[zidx(f,0)] = make_float2(0.5f*(ar+br), 0.5f*(ar-br));
        float cr = srb[(size_t)256*TT + tc]*msk;
        float ci = sib[(size_t)256*TT + tc]*msk;
        zc[zidx(f,1)] = make_float2(cr,-ci);        // brev9(256)=1, Z=conj(X[256])
      } else {
        float st,ct; __sincosf((float)k*0.006135923151542565f,&st,&ct); // pi*k/512
        float Er=0.5f*(ar+br), Ei=0.5f*(ai-bi);
        float Dr=0.5f*(ar-br), Di=0.5f*(ai+bi);
        float Or=Dr*ct-Di*st,  Oi=Dr*st+Di*ct;
        zc[zidx(f,brev9(k))]     = make_float2(Er-Oi, Ei+Or);
        zc[zidx(f,brev9(512-k))] = make_float2(Er+Oi, Or-Ei);
      }
    }

    // ---- phase 2: 512-pt inverse FFT: 4 fused radix-4 stages + 1 radix-2 ----
    for (int st=0; st<4; ++st) {
      __syncthreads();
      const int h = 1<<(2*st);
      #pragma unroll
      for (int i=0;i<4;++i) {
        int q   = pp + 32*i;                        // [0,128)
        int ilo = q & (h-1);
        int base= ((q>>(2*st))<<(2*st+2)) + ilo;    // ihi*4h + ilo
        float2 w1 = ttab[ilo<<(8-2*st)];            // W^{ilo*256/h}
        float2 w2 = ttab[ilo<<(7-2*st)];            // W^{ilo*128/h}
        float2 e0=zc[zidx(f,base)],     e1=zc[zidx(f,base+h)];
        float2 e2=zc[zidx(f,base+2*h)], e3=zc[zidx(f,base+3*h)];
        float t1r=e1.x*w1.x-e1.y*w1.y, t1i=e1.x*w1.y+e1.y*w1.x;
        float t3r=e3.x*w1.x-e3.y*w1.y, t3i=e3.x*w1.y+e3.y*w1.x;
        float arr=e0.x+t1r, ari=e0.y+t1i, brr=e0.x-t1r, bri=e0.y-t1i;
        float crr=e2.x+t3r, cri=e2.y+t3i, drr=e2.x-t3r, dri=e2.y-t3i;
        float cwr=crr*w2.x-cri*w2.y, cwi=crr*w2.y+cri*w2.x;
        float dwr=drr*w2.x-dri*w2.y, dwi=drr*w2.y+dri*w2.x;
        zc[zidx(f,base)]     = make_float2(arr+cwr, ari+cwi);
        zc[zidx(f,base+2*h)] = make_float2(arr-cwr, ari-cwi);
        zc[zidx(f,base+h)]   = make_float2(brr-dwi, bri+dwr);  // b + i*dw (W^128=+i)
        zc[zidx(f,base+3*h)] = make_float2(brr+dwi, bri-dwr);  // b - i*dw
      }
    }
    __syncthreads();
    #pragma unroll
    for (int i=0;i<8;++i) {                         // radix-2, h=256
      int q = pp + 32*i;                            // [0,256)
      float2 tw = ttab[q];
      float2 u = zc[zidx(f,q)], v = zc[zidx(f,q+256)];
      float tr=v.x*tw.x-v.y*tw.y, ti=v.x*tw.y+v.y*tw.x;
      zc[zidx(f,q)]     = make_float2(u.x+tr, u.y+ti);
      zc[zidx(f,q+256)] = make_float2(u.x-tr, u.y-ti);
    }

    // ---- phase 3: unpack real pairs, window, OLA (frames g, g+4 disjoint) ----
    for (int g=0; g<4; ++g) {
      __syncthreads();
      int slot = g + 4*(tid>>7);
      int tg   = Tbase + 8*c + slot;
      int offB = tg*HOP - L0;                       // even
      bool vt  = (tg>=0 && tg<TT);
      int mb   = tid & 127;
      #pragma unroll
      for (int i=0;i<4;++i) {
        int m = mb + 128*i;
        float2 v = zc[zidx(slot,m)];
        int j0 = 2*m;
        float w0 = 0.5f-0.5f*__cosf((float)j0    *0.006135923151542565f);
        float w1v= 0.5f-0.5f*__cosf((float)(j0+1)*0.006135923151542565f);
        int idx = offB + j0;                        // even; pair in/out together
        if (vt && idx>=0 && idx<SPAN) {
          float2 o = ola[idx>>1];
          o.x += v.x*(1.f/512.f)*w0;
          o.y += v.y*(1.f/512.f)*w1v;
          ola[idx>>1] = o;
        }
      }
    }
  }
  __syncthreads();

  // ---- finalize: divide by window^2 envelope (1.5 in interior), store ----
  const bool edge = (tile==0)|(tile==TILES-1);
  float* outb = out + (size_t)b*OUTLB;
  for (int i=0;i<7;++i) {
    int i4 = tid + 256*i;                           // float4 index in span
    int s  = 4*i4;
    int gs = tile*SPAN + s;
    if (gs < OUTLB) {
      float4 v = ((const float4*)ola)[i4];
      float r[4]={v.x,v.y,v.z,v.w};
      if (!edge) {
        #pragma unroll
        for(int e=0;e<4;++e) r[e] *= (2.f/3.f);     // Hann 4x OLA interior env=1.5
      } else {
        #pragma unroll
        for(int e=0;e<4;++e) {
          int l = L0 + s + e;
          int j0 = l & 255, tb = l >> 8;
          float env=0.f;
          #pragma unroll
          for (int mm=0;mm<4;++mm) {
            int t2 = tb-mm;
            if (t2>=0 && t2<TT) {
              float wv = 0.5f-0.5f*__cosf((float)(j0+256*mm)*0.006135923151542565f);
              env += wv*wv;
            }
          }
          r[e] /= env;
        }
      }
      *(float4*)(outb+gs) = make_float4(r[0],r[1],r[2],r[3]);
    }
  }
}

extern "C" void kernel_launch(void* const* d_in, const int* in_sizes, int n_in,
                              void* d_out, int out_size, void* d_ws, size_t ws_size,
                              hipStream_t stream) {
  const float* sr = (const float*)d_in[0];
  const float* si = (const float*)d_in[1];
  float* out = (float*)d_out;
  istft_fused<<<BB*TILES, 256, 0, stream>>>(sr, si, out);
}